// Round 1
// baseline (220.377 us; speedup 1.0000x reference)
//
#include <hip/hip_runtime.h>
#include <hip/hip_bf16.h>
#include <math.h>

typedef __bf16 bf16;
typedef __attribute__((ext_vector_type(8))) __bf16 bf16x8;
typedef __attribute__((ext_vector_type(4))) __bf16 bf16x4;
typedef __attribute__((ext_vector_type(4))) float f32x4;

#define MFMA16(a, b, c) __builtin_amdgcn_mfma_f32_16x16x32_bf16((a), (b), (c), 0, 0, 0)

// Problem dims
// B=32, T=1024, VOCAB=512, RANK=256
// x [32768, 512] f32 ; W_attn [512,768] ; b_attn[768] ; W_proj [256,512] ; b_proj[512]

// ---------------- weight convert+transpose (tiny) ----------------
__global__ __launch_bounds__(256) void cvt_wattn(const float* __restrict__ w,
                                                 bf16* __restrict__ wt) {
  int o = blockIdx.x * 256 + threadIdx.x;   // 768*512 = 393216
  int n = o >> 9, kk = o & 511;
  wt[o] = (bf16)w[kk * 768 + n];            // WT[n][k] = W[k][n]
}

__global__ __launch_bounds__(256) void cvt_wproj(const float* __restrict__ w,
                                                 bf16* __restrict__ wt) {
  int o = blockIdx.x * 256 + threadIdx.x;   // 512*256 = 131072
  int n = o >> 8, kk = o & 255;
  wt[o] = (bf16)w[kk * 512 + n];            // WT[n][k] = W[k][n]
}

// ---------------- qkv GEMM: [32768,512] x [512,768] ----------------
__global__ __launch_bounds__(256) void gemm_qkv(
    const float* __restrict__ x, const bf16* __restrict__ WT,
    const float* __restrict__ b_attn,
    bf16* __restrict__ qo, bf16* __restrict__ ko, bf16* __restrict__ vo) {
  __shared__ __attribute__((aligned(16))) bf16 As[128][40];
  __shared__ __attribute__((aligned(16))) bf16 Bs[128][40];
  const int tid = threadIdx.x;
  const int bn = blockIdx.x * 128;   // N fast (6) -> A-panel L2 reuse
  const int bm = blockIdx.y * 128;   // M (256)
  const int lane = tid & 63, wid = tid >> 6;
  const int l15 = lane & 15, lg = lane >> 4;
  const int wm = (wid >> 1) * 64, wn = (wid & 1) * 64;

  f32x4 acc[4][4] = {};

  const int srow = tid >> 1;
  const int scol = (tid & 1) * 16;
  const float* xp = x + (size_t)(bm + srow) * 512 + scol;
  const bf16* wp = WT + (size_t)(bn + srow) * 512 + scol;

  for (int kt = 0; kt < 16; ++kt) {
    f32x4 f0 = *(const f32x4*)(xp + kt * 32);
    f32x4 f1 = *(const f32x4*)(xp + kt * 32 + 4);
    f32x4 f2 = *(const f32x4*)(xp + kt * 32 + 8);
    f32x4 f3 = *(const f32x4*)(xp + kt * 32 + 12);
    bf16x8 h0, h1;
#pragma unroll
    for (int e = 0; e < 4; ++e) {
      h0[e] = (bf16)f0[e]; h0[e + 4] = (bf16)f1[e];
      h1[e] = (bf16)f2[e]; h1[e + 4] = (bf16)f3[e];
    }
    bf16x8 b0 = *(const bf16x8*)(wp + kt * 32);
    bf16x8 b1 = *(const bf16x8*)(wp + kt * 32 + 8);
    *(bf16x8*)&As[srow][scol] = h0;
    *(bf16x8*)&As[srow][scol + 8] = h1;
    *(bf16x8*)&Bs[srow][scol] = b0;
    *(bf16x8*)&Bs[srow][scol + 8] = b1;
    __syncthreads();
    bf16x8 af[4], bfr[4];
#pragma unroll
    for (int mi = 0; mi < 4; ++mi)
      af[mi] = *(const bf16x8*)&As[wm + mi * 16 + l15][lg * 8];
#pragma unroll
    for (int ni = 0; ni < 4; ++ni)
      bfr[ni] = *(const bf16x8*)&Bs[wn + ni * 16 + l15][lg * 8];
#pragma unroll
    for (int mi = 0; mi < 4; ++mi)
#pragma unroll
      for (int ni = 0; ni < 4; ++ni)
        acc[mi][ni] = MFMA16(af[mi], bfr[ni], acc[mi][ni]);
    __syncthreads();
  }

#pragma unroll
  for (int ni = 0; ni < 4; ++ni) {
    int gc = bn + wn + ni * 16 + l15;
    float bias = b_attn[gc];
    int seg = gc >> 8;         // 0=q 1=k 2=v  (frag never crosses a 256 boundary)
    int cc = gc & 255;
    bf16* op = (seg == 0) ? qo : ((seg == 1) ? ko : vo);
#pragma unroll
    for (int mi = 0; mi < 4; ++mi) {
      int gr = bm + wm + mi * 16 + lg * 4;
#pragma unroll
      for (int r = 0; r < 4; ++r) {
        float v = acc[mi][ni][r] + bias;
        op[(size_t)(gr + r) * 256 + cc] = (bf16)v;
      }
    }
  }
}

// ---------------- v -> v^T : [32][1024][256] -> [32][256][1024] ----------------
__global__ __launch_bounds__(256) void transpose_v(const bf16* __restrict__ v,
                                                   bf16* __restrict__ vt) {
  __shared__ bf16 tile[32][33];
  const int b = blockIdx.z;
  const int t0 = blockIdx.x * 32;
  const int d0 = blockIdx.y * 32;
  const int tid = threadIdx.x;
  const int r = tid >> 3, c4 = (tid & 7) * 4;
  bf16x4 in = *(const bf16x4*)(v + (size_t)(b * 1024 + t0 + r) * 256 + d0 + c4);
  tile[r][c4] = in[0]; tile[r][c4 + 1] = in[1];
  tile[r][c4 + 2] = in[2]; tile[r][c4 + 3] = in[3];
  __syncthreads();
  bf16x4 o;
  o[0] = tile[c4][r]; o[1] = tile[c4 + 1][r];
  o[2] = tile[c4 + 2][r]; o[3] = tile[c4 + 3][r];
  *(bf16x4*)(vt + (size_t)(b * 256 + d0 + r) * 1024 + t0 + c4) = o;
}

// ---------------- flash attention, causal, scale 1/16 ----------------
__global__ __launch_bounds__(256) void attn_fwd(
    const bf16* __restrict__ q, const bf16* __restrict__ k,
    const bf16* __restrict__ vt, bf16* __restrict__ y) {
  __shared__ __attribute__((aligned(16))) bf16 Ks[64][264];   // [s][d], +8 pad
  __shared__ __attribute__((aligned(16))) bf16 Vt[256][72];   // [d][s], +8 pad
  __shared__ __attribute__((aligned(16))) bf16 Ps[4][16][72]; // per-wave P
  const int tid = threadIdx.x, lane = tid & 63, wid = tid >> 6;
  const int l15 = lane & 15, lg = lane >> 4;
  const int b = blockIdx.y;
  const int bx = blockIdx.x;
  // anti-diagonal remap: pair heavy causal tiles with light ones
  const int qt = (bx & 1) ? (15 - (bx >> 1)) : (bx >> 1);
  const int qbase = qt * 64;
  const int q0 = qbase + wid * 16;

  bf16x8 qf[8];
  {
    const bf16* qp = q + (size_t)(b * 1024 + q0 + l15) * 256 + lg * 8;
#pragma unroll
    for (int d = 0; d < 8; ++d) qf[d] = *(const bf16x8*)(qp + d * 32);
  }
  f32x4 o[16] = {};
  float mrow[4] = {-1e30f, -1e30f, -1e30f, -1e30f};
  float lrow[4] = {0.f, 0.f, 0.f, 0.f};

  const int ntiles = qt + 1;
  for (int tt = 0; tt < ntiles; ++tt) {
    const int kv0 = tt * 64;
#pragma unroll
    for (int i = 0; i < 8; ++i) {
      int chunk = tid + i * 256;                 // 64 rows x 32 chunks
      int row = chunk >> 5, c8 = (chunk & 31) * 8;
      *(bf16x8*)&Ks[row][c8] =
          *(const bf16x8*)(k + (size_t)(b * 1024 + kv0 + row) * 256 + c8);
    }
#pragma unroll
    for (int i = 0; i < 8; ++i) {
      int chunk = tid + i * 256;                 // 256 d-rows x 8 chunks
      int d = chunk >> 3, s8 = (chunk & 7) * 8;
      *(bf16x8*)&Vt[d][s8] =
          *(const bf16x8*)(vt + (size_t)(b * 256 + d) * 1024 + kv0 + s8);
    }
    __syncthreads();

    // S = Q K^T  (16q x 64s per wave)
    f32x4 s[4] = {};
#pragma unroll
    for (int nf = 0; nf < 4; ++nf)
#pragma unroll
      for (int dc = 0; dc < 8; ++dc) {
        bf16x8 kb = *(const bf16x8*)&Ks[nf * 16 + l15][dc * 32 + lg * 8];
        s[nf] = MFMA16(qf[dc], kb, s[nf]);
      }

    // scale + causal mask + online softmax (row r lives in reg r of lane-group lg)
#pragma unroll
    for (int r = 0; r < 4; ++r) {
      const int qrow = q0 + lg * 4 + r;
      float mx = -1e30f;
#pragma unroll
      for (int nf = 0; nf < 4; ++nf) {
        int scol = kv0 + nf * 16 + l15;
        float sv = s[nf][r] * 0.0625f;
        sv = (scol > qrow) ? -1e30f : sv;
        s[nf][r] = sv;
        mx = fmaxf(mx, sv);
      }
#pragma unroll
      for (int m = 1; m < 16; m <<= 1) mx = fmaxf(mx, __shfl_xor(mx, m, 64));
      float mnew = fmaxf(mrow[r], mx);
      float corr = __expf(mrow[r] - mnew);
      mrow[r] = mnew;
      float rsum = 0.f;
#pragma unroll
      for (int nf = 0; nf < 4; ++nf) {
        float p = __expf(s[nf][r] - mnew);
        s[nf][r] = p;
        rsum += p;
      }
#pragma unroll
      for (int m = 1; m < 16; m <<= 1) rsum += __shfl_xor(rsum, m, 64);
      lrow[r] = lrow[r] * corr + rsum;
#pragma unroll
      for (int df = 0; df < 16; ++df) o[df][r] *= corr;
    }

    // P (C-frag layout) -> LDS -> A-frag layout
#pragma unroll
    for (int nf = 0; nf < 4; ++nf)
#pragma unroll
      for (int r = 0; r < 4; ++r)
        Ps[wid][lg * 4 + r][nf * 16 + l15] = (bf16)s[nf][r];
    // same-wave LDS RAW: compiler inserts lgkmcnt; no block barrier needed here

#pragma unroll
    for (int kk = 0; kk < 2; ++kk) {
      bf16x8 pa = *(const bf16x8*)&Ps[wid][l15][kk * 32 + lg * 8];
#pragma unroll
      for (int df = 0; df < 16; ++df) {
        bf16x8 vb = *(const bf16x8*)&Vt[df * 16 + l15][kk * 32 + lg * 8];
        o[df] = MFMA16(pa, vb, o[df]);
      }
    }
    __syncthreads();   // protect Ks/Vt before next tile's staging
  }

  const size_t ybase = (size_t)(b * 1024 + q0 + lg * 4) * 256 + l15;
#pragma unroll
  for (int r = 0; r < 4; ++r) {
    float inv = 1.f / lrow[r];
#pragma unroll
    for (int df = 0; df < 16; ++df)
      y[ybase + (size_t)r * 256 + df * 16] = (bf16)(o[df][r] * inv);
  }
}

// ---------------- proj GEMM + bias + exact GELU ----------------
__global__ __launch_bounds__(256) void gemm_proj(
    const bf16* __restrict__ y, const bf16* __restrict__ WT,
    const float* __restrict__ b_proj, float* __restrict__ out) {
  __shared__ __attribute__((aligned(16))) bf16 As[128][40];
  __shared__ __attribute__((aligned(16))) bf16 Bs[128][40];
  const int tid = threadIdx.x;
  const int bn = blockIdx.x * 128;  // N fast (4)
  const int bm = blockIdx.y * 128;  // M (256)
  const int lane = tid & 63, wid = tid >> 6;
  const int l15 = lane & 15, lg = lane >> 4;
  const int wm = (wid >> 1) * 64, wn = (wid & 1) * 64;
  f32x4 acc[4][4] = {};
  const int srow = tid >> 1, scol = (tid & 1) * 16;
  const bf16* yp = y + (size_t)(bm + srow) * 256 + scol;
  const bf16* wp = WT + (size_t)(bn + srow) * 256 + scol;
  for (int kt = 0; kt < 8; ++kt) {
    bf16x8 a0 = *(const bf16x8*)(yp + kt * 32);
    bf16x8 a1 = *(const bf16x8*)(yp + kt * 32 + 8);
    bf16x8 b0 = *(const bf16x8*)(wp + kt * 32);
    bf16x8 b1 = *(const bf16x8*)(wp + kt * 32 + 8);
    *(bf16x8*)&As[srow][scol] = a0;  *(bf16x8*)&As[srow][scol + 8] = a1;
    *(bf16x8*)&Bs[srow][scol] = b0;  *(bf16x8*)&Bs[srow][scol + 8] = b1;
    __syncthreads();
    bf16x8 af[4], bfr[4];
#pragma unroll
    for (int mi = 0; mi < 4; ++mi)
      af[mi] = *(const bf16x8*)&As[wm + mi * 16 + l15][lg * 8];
#pragma unroll
    for (int ni = 0; ni < 4; ++ni)
      bfr[ni] = *(const bf16x8*)&Bs[wn + ni * 16 + l15][lg * 8];
#pragma unroll
    for (int mi = 0; mi < 4; ++mi)
#pragma unroll
      for (int ni = 0; ni < 4; ++ni)
        acc[mi][ni] = MFMA16(af[mi], bfr[ni], acc[mi][ni]);
    __syncthreads();
  }
#pragma unroll
  for (int ni = 0; ni < 4; ++ni) {
    int gc = bn + wn + ni * 16 + l15;
    float bias = b_proj[gc];
#pragma unroll
    for (int mi = 0; mi < 4; ++mi) {
      int gr = bm + wm + mi * 16 + lg * 4;
#pragma unroll
      for (int r = 0; r < 4; ++r) {
        float v = acc[mi][ni][r] + bias;
        float g = 0.5f * v * (1.0f + erff(v * 0.70710678118654752f));
        out[(size_t)(gr + r) * 512 + gc] = g;
      }
    }
  }
}

extern "C" void kernel_launch(void* const* d_in, const int* in_sizes, int n_in,
                              void* d_out, int out_size, void* d_ws, size_t ws_size,
                              hipStream_t stream) {
  const float* x      = (const float*)d_in[0];
  const float* W_attn = (const float*)d_in[1];
  const float* b_attn = (const float*)d_in[2];
  const float* W_proj = (const float*)d_in[3];
  const float* b_proj = (const float*)d_in[4];
  float* out = (float*)d_out;
  char* ws = (char*)d_ws;

  const size_t SZ = 16777216;  // one [32,1024,256] bf16 buffer
  bf16* WT1 = (bf16*)(ws);                       // 768*512*2 = 786432
  bf16* WT2 = (bf16*)(ws + 786432);              // 512*256*2 = 262144
  bf16* qb  = (bf16*)(ws + 1048576);
  bf16* kb  = (bf16*)(ws + 1048576 + SZ);
  bf16* vb  = (bf16*)(ws + 1048576 + 2 * SZ);
  bf16* vtb = (bf16*)(ws + 1048576 + 3 * SZ);
  bf16* yb  = vb;  // v is dead after transpose_v; reuse its slot for y

  cvt_wattn<<<dim3(1536), dim3(256), 0, stream>>>(W_attn, WT1);
  cvt_wproj<<<dim3(512), dim3(256), 0, stream>>>(W_proj, WT2);
  gemm_qkv<<<dim3(6, 256), dim3(256), 0, stream>>>(x, WT1, b_attn, qb, kb, vb);
  transpose_v<<<dim3(32, 8, 32), dim3(256), 0, stream>>>(vb, vtb);
  attn_fwd<<<dim3(16, 32), dim3(256), 0, stream>>>(qb, kb, vtb, yb);
  gemm_proj<<<dim3(4, 256), dim3(256), 0, stream>>>(yb, WT2, b_proj, out);
}